// Round 16
// baseline (270.410 us; speedup 1.0000x reference)
//
#include <hip/hip_runtime.h>
#include <cstdint>

#define NROWS 32768
#define HD    1024
#define KSEL  8192
#define LN_EPS 1e-12f
#define PD_EPS 1e-6f

typedef unsigned short u16;
typedef __bf16 bf16x8 __attribute__((ext_vector_type(8)));
typedef float  f32x4  __attribute__((ext_vector_type(4)));
typedef int    v8i    __attribute__((ext_vector_type(8)));
typedef int    v4i    __attribute__((ext_vector_type(4)));

__device__ inline u16 f2bf(float f) {
    union { float f; uint32_t u; } x; x.f = f;
    uint32_t r = (x.u + 0x7fffu + ((x.u >> 16) & 1u)) >> 16;
    return (u16)r;
}

__device__ inline uint2 pack4(float a, float b, float c, float d) {
    uint2 r;
    r.x = (uint32_t)f2bf(a) | ((uint32_t)f2bf(b) << 16);
    r.y = (uint32_t)f2bf(c) | ((uint32_t)f2bf(d) << 16);
    return r;
}

// ---------------- fp8 e4m3 packing ----------------
__device__ inline uint32_t enc_e4m3(float f) {
    union { float f; uint32_t u; } x; x.f = f;
    uint32_t s = (x.u >> 31) << 7;
    float a = fabsf(f);
    if (a >= 448.f) return s | 0x7e;
    if (a < 0.001953125f) {
        int q = (int)(a * 512.f + 0.5f);
        return s | (uint32_t)q;
    }
    int e; float m = frexpf(a, &e);
    int E = e - 1 + 7;
    int q = (int)((m * 2.f - 1.f) * 8.f + 0.5f);
    if (q == 8) { q = 0; E += 1; }
    if (E >= 16) return s | 0x7e;
    if (E <= 0) { int qq = (int)(a * 512.f + 0.5f); return s | (uint32_t)qq; }
    return s | (uint32_t)(E << 3) | (uint32_t)q;
}

__device__ inline uint32_t pack4_f8(float a, float b, float c, float d) {
#if defined(__has_builtin) && __has_builtin(__builtin_amdgcn_cvt_pk_fp8_f32)
    int v = __builtin_amdgcn_cvt_pk_fp8_f32(a, b, 0, false);
    v = __builtin_amdgcn_cvt_pk_fp8_f32(c, d, v, true);
    return (uint32_t)v;
#else
    return enc_e4m3(a) | (enc_e4m3(b) << 8) | (enc_e4m3(c) << 16) | (enc_e4m3(d) << 24);
#endif
}

// ---------------- mask compaction (layout-robust) ----------------
__global__ void compact_mask_k(const uint8_t* mb, const int32_t* mi, int* idx) {
    __shared__ int cnt[1024];
    __shared__ int tmp[1024];
    __shared__ int mode_s;
    const int t = threadIdx.x;
    const int per = NROWS / 1024;      // 32
    const int base = t * per;
    int c0 = 0;
    for (int i = 0; i < per; ++i) c0 += (mb[base + i] != 0);
    tmp[t] = c0;
    __syncthreads();
    for (int off = 512; off > 0; off >>= 1) {
        if (t < off) tmp[t] += tmp[t + off];
        __syncthreads();
    }
    if (t == 0) mode_s = (tmp[0] == KSEL) ? 0 : 1;
    __syncthreads();
    const int mode = mode_s;
    int c = c0;
    if (mode) { c = 0; for (int i = 0; i < per; ++i) c += (mi[base + i] != 0); }
    cnt[t] = c;
    __syncthreads();
    for (int off = 1; off < 1024; off <<= 1) {
        int add = (t >= off) ? cnt[t - off] : 0;
        __syncthreads();
        cnt[t] += add;
        __syncthreads();
    }
    int pos = cnt[t] - c;
    for (int i = 0; i < per; ++i) {
        bool v = mode ? (mi[base + i] != 0) : (mb[base + i] != 0);
        if (v) idx[pos++] = base + i;
    }
}

// -- gather selected rows -> bf16(preds) + fp8(labels), fused with W->bf16 --
__global__ void gather_conv_k(const float* __restrict__ msp, const float* __restrict__ lab,
                              const int* __restrict__ idx, const float* __restrict__ W,
                              u16* __restrict__ predsB, uint8_t* __restrict__ labelsB8,
                              u16* __restrict__ Wb) {
    const int b = blockIdx.x;
    const int t = threadIdx.x;
    if (b < KSEL) {
        const int src = idx[b];
        float4 p = *(const float4*)(msp + (size_t)src * HD + t * 4);
        float4 q = *(const float4*)(lab + (size_t)src * HD + t * 4);
        *(uint2*)(predsB + (size_t)b * HD + t * 4) = pack4(p.x, p.y, p.z, p.w);
        *(uint32_t*)(labelsB8 + (size_t)b * HD + t * 4) = pack4_f8(q.x, q.y, q.z, q.w);
    } else {
        const int i = ((b - KSEL) * 256 + t) * 4;   // 1024 blocks cover HD*HD
        float4 v = *(const float4*)(W + i);
        *(uint2*)(Wb + i) = pack4(v.x, v.y, v.z, v.w);
    }
}

// =======================================================================
// bf16 GEMM (GEMM1): r11 structure verbatim — 256x256 tile, BK=64,
// 8 waves, acc[8][4] 16x16x32, full-tile operand prefetch, one counted
// vmcnt(4)+barrier per tile, slot^(row&7) swizzle (both-sides).
// =======================================================================
#define STAGE(XPTR, ROWBASE, KT, I, LBASE) do {                                      \
    const int f_ = (I) * 512 + tid;                                                  \
    const int r_ = f_ >> 3;                                                          \
    const int sp_ = (f_ & 7) ^ (r_ & 7);                                             \
    const u16* g_ = (XPTR) + (size_t)((ROWBASE) + r_) * Kd + koff + (KT) * 64 + sp_ * 8; \
    __builtin_amdgcn_global_load_lds(                                                \
        (const __attribute__((address_space(1))) void*)g_,                           \
        (__attribute__((address_space(3))) void*)(lds + (LBASE) + f_ * 8), 16, 0, 0);\
} while (0)

__global__ __launch_bounds__(512, 2)
void gemm256a_k(const u16* __restrict__ A, const u16* __restrict__ Bt,
                float* __restrict__ C, int M, int N, int Kd) {
    extern __shared__ u16 lds[];
    const int nwg = (M >> 8) * (N >> 8);
    int bid = blockIdx.x;
    const int half = (bid >= nwg) ? 1 : 0;
    if (half) bid -= nwg;
    const int KdH = Kd >> 1;
    const int koff = half * KdH;
    float* Cp = C + (size_t)half * ((size_t)M * N);

    const int nx  = N >> 8;
    int wg  = ((nwg & 7) == 0) ? ((bid & 7) * (nwg >> 3) + (bid >> 3)) : bid;
    const int bm = wg / nx, bn = wg % nx;
    const size_t brow = (size_t)bm << 8, bcol = (size_t)bn << 8;
    const int tid = threadIdx.x;
    const int l = tid & 63, wid = tid >> 6;
    const int wm = wid >> 2, wn = wid & 3;
    const int lr = l & 15, lq = l >> 4;
    const int sw = lr & 7;
    f32x4 acc[8][4] = {};
    const int arow = (wm * 128 + lr) * 64;
    const int brow2 = (wn * 64 + lr) * 64;
    const int s0 = (lq ^ sw) * 8;
    const int s1 = ((4 + lq) ^ sw) * 8;
    #pragma unroll
    for (int i = 0; i < 4; ++i) STAGE(A,  brow, 0, i, 0);
    #pragma unroll
    for (int i = 0; i < 4; ++i) STAGE(Bt, bcol, 0, i, 49152);
    #pragma unroll
    for (int i = 0; i < 4; ++i) STAGE(A,  brow, 1, i, 16384);
    asm volatile("s_waitcnt vmcnt(4)" ::: "memory");
    __builtin_amdgcn_s_barrier();
    const int T = KdH >> 6;
    int abi = 0;
    #pragma unroll 1
    for (int t = 0; t < T; ++t) {
        const int aB = abi * 16384;
        const int bB = 49152 + (t & 1) * 16384;
        const int aN = (abi >= 1 ? abi - 1 : 2) * 16384;
        const int bN = 49152 + ((t + 1) & 1) * 16384;
        bf16x8 a0[8], b0[4], a1[8], b1[4];
        #pragma unroll
        for (int mi = 0; mi < 8; ++mi)
            a0[mi] = *(const bf16x8*)(lds + aB + arow + mi * 1024 + s0);
        #pragma unroll
        for (int ni = 0; ni < 4; ++ni)
            b0[ni] = *(const bf16x8*)(lds + bB + brow2 + ni * 1024 + s0);
        #pragma unroll
        for (int mi = 0; mi < 8; ++mi)
            a1[mi] = *(const bf16x8*)(lds + aB + arow + mi * 1024 + s1);
        #pragma unroll
        for (int ni = 0; ni < 4; ++ni)
            b1[ni] = *(const bf16x8*)(lds + bB + brow2 + ni * 1024 + s1);
        if (t + 1 < T) {
            STAGE(Bt, bcol, t + 1, 0, bN); STAGE(Bt, bcol, t + 1, 1, bN);
            STAGE(Bt, bcol, t + 1, 2, bN); STAGE(Bt, bcol, t + 1, 3, bN);
        }
        if (t + 2 < T) {
            STAGE(A, brow, t + 2, 0, aN); STAGE(A, brow, t + 2, 1, aN);
            STAGE(A, brow, t + 2, 2, aN); STAGE(A, brow, t + 2, 3, aN);
        }
        #pragma unroll
        for (int mi = 0; mi < 8; ++mi) {
            #pragma unroll
            for (int ni = 0; ni < 4; ++ni)
                acc[mi][ni] = __builtin_amdgcn_mfma_f32_16x16x32_bf16(a0[mi], b0[ni], acc[mi][ni], 0, 0, 0);
        }
        #pragma unroll
        for (int mi = 0; mi < 8; ++mi) {
            #pragma unroll
            for (int ni = 0; ni < 4; ++ni)
                acc[mi][ni] = __builtin_amdgcn_mfma_f32_16x16x32_bf16(a1[mi], b1[ni], acc[mi][ni], 0, 0, 0);
        }
        if (t < T - 2) { asm volatile("s_waitcnt vmcnt(4)" ::: "memory"); }
        else           { asm volatile("s_waitcnt vmcnt(0)" ::: "memory"); }
        __builtin_amdgcn_s_barrier();
        abi = (abi == 2) ? 0 : abi + 1;
    }
    #pragma unroll
    for (int m = 0; m < 8; ++m) {
        const size_t rb = brow + wm * 128 + m * 16 + lq * 4;
        #pragma unroll
        for (int n = 0; n < 4; ++n) {
            const size_t cb = bcol + wn * 64 + n * 16 + lr;
            #pragma unroll
            for (int rr = 0; rr < 4; ++rr)
                Cp[(rb + rr) * (size_t)N + cb] = acc[m][n][rr];
        }
    }
}

// =======================================================================
// MX-fp8 GEMM (GEMM2): ROUND-16 CHANGE — 128x128 tile, 256 threads
// (4 waves 2x2), BK=128, LDS 80KB (A triple 3x16KB @0/16384/32768,
// B double @49152/65536) -> 2 WGs/CU. Rationale: 9 rounds of intra-WG
// schedule levers all plateaued ~2x above the pipe floor because the
// single WG's barrier-coupled waves idle the MFMA pipe together; with 2
// INDEPENDENT WGs per CU, one WG's MFMA leg covers the other's barrier
// stall (m114/m97 mechanism; guide: "128-sq for simple 2-barrier loops").
// mfma_scale 16x16x128 with unit scales (bit-identical to fp8, 2x rate,
// 32B-contiguous fragments -> b128 reads, 0 conflicts — r15 verified).
// Same counted-vmcnt proof (4 loads/buffer): tile-end vmcnt(4) keeps
// A(t+2) in flight. Stats: 2 wn-partials/row, 64 col-tiles; pst 4MB.
// =======================================================================
#define STAGE8(XPTR, ROWBASE, KT, I, LBASE) do {                                     \
    const int f_ = (I) * 256 + tid;                                                  \
    const int r_ = f_ >> 3;                                                          \
    const int sp_ = (f_ & 7) ^ (r_ & 7);                                             \
    const uint8_t* g_ = (XPTR) + (size_t)((ROWBASE) + r_) * Kd + (KT) * 128 + sp_ * 16; \
    __builtin_amdgcn_global_load_lds(                                                \
        (const __attribute__((address_space(1))) void*)g_,                           \
        (__attribute__((address_space(3))) void*)(lds8 + (LBASE) + f_ * 16), 16, 0, 0);\
} while (0)

__device__ inline v8i ld_frag32(const uint8_t* p0, const uint8_t* p1) {
    v4i lo = *(const v4i*)p0;
    v4i hi = *(const v4i*)p1;
    v8i r;
    r[0] = lo[0]; r[1] = lo[1]; r[2] = lo[2]; r[3] = lo[3];
    r[4] = hi[0]; r[5] = hi[1]; r[6] = hi[2]; r[7] = hi[3];
    return r;
}

__global__ __launch_bounds__(256, 2)
void gemm256s_k(const uint8_t* __restrict__ A, const uint8_t* __restrict__ Bt,
                float* __restrict__ C, int M, int N, int Kd,
                float2* __restrict__ pst) {
    extern __shared__ u16 lds[];
    uint8_t* lds8 = (uint8_t*)lds;
    const int nx  = N >> 7;                    // 64 col tiles
    const int nwg = (M >> 7) * nx;             // 4096
    int bid = blockIdx.x;
    int wg  = ((nwg & 7) == 0) ? ((bid & 7) * (nwg >> 3) + (bid >> 3)) : bid;
    const int bm = wg / nx, bn = wg % nx;
    const size_t brow = (size_t)bm << 7, bcol = (size_t)bn << 7;
    const int tid = threadIdx.x;
    const int l = tid & 63, wid = tid >> 6;    // 4 waves
    const int wm = wid >> 1, wn = wid & 1;     // 2 x 2
    const int lr = l & 15, lq = l >> 4;
    const int sw = lr & 7;
    f32x4 acc[4][4] = {};
    const int arow = (wm * 64 + lr) * 128;     // byte offsets, 128B rows
    const int brow2 = (wn * 64 + lr) * 128;
    const int f0 = ((lq * 2 + 0) ^ sw) * 16;
    const int f1 = ((lq * 2 + 1) ^ sw) * 16;

    #pragma unroll
    for (int i = 0; i < 4; ++i) STAGE8(A,  brow, 0, i, 0);
    #pragma unroll
    for (int i = 0; i < 4; ++i) STAGE8(Bt, bcol, 0, i, 49152);
    #pragma unroll
    for (int i = 0; i < 4; ++i) STAGE8(A,  brow, 1, i, 16384);
    asm volatile("s_waitcnt vmcnt(4)" ::: "memory");
    __builtin_amdgcn_s_barrier();

    const int T = Kd >> 7;      // 8 K-tiles of 128
    int abi = 0;
    #pragma unroll 1
    for (int t = 0; t < T; ++t) {
        const int aB = abi * 16384;
        const int bB = 49152 + (t & 1) * 16384;
        const int aN = (abi >= 1 ? abi - 1 : 2) * 16384;
        const int bN = 49152 + ((t + 1) & 1) * 16384;
        v8i a8[4], b8[4];
        #pragma unroll
        for (int mi = 0; mi < 4; ++mi)
            a8[mi] = ld_frag32(lds8 + aB + arow + mi * 2048 + f0,
                               lds8 + aB + arow + mi * 2048 + f1);
        #pragma unroll
        for (int ni = 0; ni < 4; ++ni)
            b8[ni] = ld_frag32(lds8 + bB + brow2 + ni * 2048 + f0,
                               lds8 + bB + brow2 + ni * 2048 + f1);
        if (t + 1 < T) {
            STAGE8(Bt, bcol, t + 1, 0, bN); STAGE8(Bt, bcol, t + 1, 1, bN);
            STAGE8(Bt, bcol, t + 1, 2, bN); STAGE8(Bt, bcol, t + 1, 3, bN);
        }
        if (t + 2 < T) {
            STAGE8(A, brow, t + 2, 0, aN); STAGE8(A, brow, t + 2, 1, aN);
            STAGE8(A, brow, t + 2, 2, aN); STAGE8(A, brow, t + 2, 3, aN);
        }
        #pragma unroll
        for (int mi = 0; mi < 4; ++mi) {
            #pragma unroll
            for (int ni = 0; ni < 4; ++ni)
                acc[mi][ni] = __builtin_amdgcn_mfma_scale_f32_16x16x128_f8f6f4(
                    a8[mi], b8[ni], acc[mi][ni],
                    0, 0,                      // cbsz=fp8, blgp=fp8
                    0, 0x7f7f7f7f,             // A scale: e8m0 1.0
                    0, 0x7f7f7f7f);            // B scale: e8m0 1.0
        }
        if (t < T - 2) { asm volatile("s_waitcnt vmcnt(4)" ::: "memory"); }
        else           { asm volatile("s_waitcnt vmcnt(0)" ::: "memory"); }
        __builtin_amdgcn_s_barrier();
        abi = (abi == 2) ? 0 : abi + 1;
    }

    // epilogue: per-m stats (native __expf) interleaved with C stores.
    float2* sbuf = (float2*)lds8;              // [128][3] float2, padded
    #pragma unroll
    for (int m = 0; m < 4; ++m) {
        #pragma unroll
        for (int rr = 0; rr < 4; ++rr) {
            float v0 = acc[m][0][rr], v1 = acc[m][1][rr];
            float v2 = acc[m][2][rr], v3 = acc[m][3][rr];
            float mx = fmaxf(fmaxf(v0, v1), fmaxf(v2, v3));
            #pragma unroll
            for (int o = 1; o < 16; o <<= 1) mx = fmaxf(mx, __shfl_xor(mx, o));
            float se = __expf(v0 - mx) + __expf(v1 - mx) + __expf(v2 - mx) + __expf(v3 - mx);
            #pragma unroll
            for (int o = 1; o < 16; o <<= 1) se += __shfl_xor(se, o);
            if (lr == 0) {
                const int rl = wm * 64 + m * 16 + lq * 4 + rr;
                sbuf[rl * 3 + wn] = make_float2(mx, se);
            }
        }
        const size_t rb = brow + wm * 64 + m * 16 + lq * 4;
        #pragma unroll
        for (int n = 0; n < 4; ++n) {
            const size_t cb = bcol + wn * 64 + n * 16 + lr;
            #pragma unroll
            for (int rr = 0; rr < 4; ++rr)
                C[(rb + rr) * (size_t)N + cb] = acc[m][n][rr];
        }
    }
    asm volatile("s_waitcnt lgkmcnt(0)" ::: "memory");
    __builtin_amdgcn_s_barrier();
    if (tid < 128) {
        const float2 p0 = sbuf[tid * 3 + 0], p1 = sbuf[tid * 3 + 1];
        const float M2 = fmaxf(p0.x, p1.x);
        const float S2 = p0.y * __expf(p0.x - M2) + p1.y * __expf(p1.x - M2);
        pst[(brow + tid) * (size_t)nx + bn] = make_float2(M2, S2);
    }
}

// ------- final per-row loss from 64 partials + diagonal (64-lane wave) --
__global__ __launch_bounds__(256)
void loss_final_k(const float2* __restrict__ pst, const float* __restrict__ logits,
                  float* __restrict__ peld, float* __restrict__ pelp) {
    const int tid = threadIdx.x;
    const int wv = tid >> 6, lane = tid & 63;
    const int row = blockIdx.x * 4 + wv;
    const float2 p = pst[(size_t)row * 64 + lane];
    const float d = logits[(size_t)row * (KSEL + 1)];   // diagonal
    float M = p.x;
    #pragma unroll
    for (int o = 1; o < 64; o <<= 1) M = fmaxf(M, __shfl_xor(M, o));
    float S = p.y * __expf(p.x - M);
    #pragma unroll
    for (int o = 1; o < 64; o <<= 1) S += __shfl_xor(S, o);
    if (lane == 0) {
        const float pi = __expf(d - M) / S;
        peld[row] = 2.0f - 2.0f * pi + (float)(KSEL - 2) * PD_EPS;
        pelp[row] = M + __logf(S) - d;
    }
}

// ---------------- block reduce helpers ----------------
__device__ inline float blockSum(float v, float* red) {
    #pragma unroll
    for (int o = 32; o > 0; o >>= 1) v += __shfl_down(v, o);
    __syncthreads();
    if ((threadIdx.x & 63) == 0) red[threadIdx.x >> 6] = v;
    __syncthreads();
    return red[0] + red[1] + red[2] + red[3];
}

// ------- bias + LayerNorm (sum of 2 split-K planes) -> fp8 ----------
__global__ void ln_k(const float* __restrict__ Hp0, const float* __restrict__ Hp1,
                     const float* __restrict__ bias,
                     const float* __restrict__ gamma, const float* __restrict__ beta,
                     uint8_t* __restrict__ Hb8) {
    __shared__ float red[4];
    const int r = blockIdx.x, t = threadIdx.x;
    float4 x4 = *(const float4*)(Hp0 + (size_t)r * HD + t * 4);
    float4 y4 = *(const float4*)(Hp1 + (size_t)r * HD + t * 4);
    float4 b4 = *(const float4*)(bias + t * 4);
    float x[4] = { x4.x + y4.x + b4.x, x4.y + y4.y + b4.y,
                   x4.z + y4.z + b4.z, x4.w + y4.w + b4.w };
    float s = x[0] + x[1] + x[2] + x[3];
    float mu = blockSum(s, red) * (1.0f / HD);
    float d0 = x[0] - mu, d1 = x[1] - mu, d2 = x[2] - mu, d3 = x[3] - mu;
    float vs = d0 * d0 + d1 * d1 + d2 * d2 + d3 * d3;
    float var = blockSum(vs, red) * (1.0f / HD);
    float rs = rsqrtf(var + LN_EPS);
    float4 g4 = *(const float4*)(gamma + t * 4);
    float4 e4 = *(const float4*)(beta + t * 4);
    float y0 = d0 * rs * g4.x + e4.x;
    float y1 = d1 * rs * g4.y + e4.y;
    float y2 = d2 * rs * g4.z + e4.z;
    float y3 = d3 * rs * g4.w + e4.w;
    *(uint32_t*)(Hb8 + (size_t)r * HD + t * 4) = pack4_f8(y0, y1, y2, y3);
}

// ---------------- deterministic two-stage f64 reduction ----------------
__global__ __launch_bounds__(1024)
void reduce_k(const float* __restrict__ peld, const float* __restrict__ pelp,
              float* __restrict__ scalars) {
    __shared__ double red[4][16];
    const int t = threadIdx.x;
    double a = 0.0, b = 0.0, c = 0.0, d = 0.0;
    for (int i = t; i < KSEL; i += 1024) {
        const double pd = (double)peld[i];
        const double pp = (double)pelp[i];
        a += pd; b += pd * pd; c += pp; d += pp * pp;
    }
    #pragma unroll
    for (int o = 32; o > 0; o >>= 1) {
        a += __shfl_down(a, o); b += __shfl_down(b, o);
        c += __shfl_down(c, o); d += __shfl_down(d, o);
    }
    const int wv = t >> 6;
    if ((t & 63) == 0) { red[0][wv] = a; red[1][wv] = b; red[2][wv] = c; red[3][wv] = d; }
    __syncthreads();
    if (t == 0) {
        double s1 = 0, s2 = 0, s3 = 0, s4 = 0;
        #pragma unroll
        for (int i = 0; i < 16; ++i) { s1 += red[0][i]; s2 += red[1][i]; s3 += red[2][i]; s4 += red[3][i]; }
        const double Kd = (double)KSEL;
        const double denom = Kd + 1e-5;
        scalars[0] = (float)(s1 / denom);
        scalars[1] = (float)(s3 / denom);
        scalars[2] = (float)((s2 - s1 * s1 / Kd) / (Kd - 1.0));
        scalars[3] = (float)((s4 - s3 * s3 / Kd) / (Kd - 1.0));
    }
}

extern "C" void kernel_launch(void* const* d_in, const int* in_sizes, int n_in,
                              void* d_out, int out_size, void* d_ws, size_t ws_size,
                              hipStream_t stream) {
    const float* msp   = (const float*)d_in[0];
    const float* lab   = (const float*)d_in[1];
    const void*  mask  = d_in[2];
    const float* W     = (const float*)d_in[3];
    const float* bias  = (const float*)d_in[4];
    const float* gamma = (const float*)d_in[5];
    const float* beta  = (const float*)d_in[6];
    float* out = (float*)d_out;
    char*  ws  = (char*)d_ws;

    int*     idx      = (int*)ws;                            // 32 KB
    u16*     wBf      = (u16*)(ws + 65536);                  // 2 MB
    uint8_t* labelsB8 = (uint8_t*)(ws + (size_t)(4  << 20)); // 8 MB
    uint8_t* hB8      = (uint8_t*)(ws + (size_t)(20 << 20)); // 8 MB (20..28MB)
    float2*  pst      = (float2*)(ws + (size_t)(28 << 20));  // 4 MB (28..32MB)
    u16*     predsB   = (u16*)d_out;                         // 16 MB scratch
    float*   hPre     = out + ((size_t)8 << 20);             // 2 planes x 32 MB

    float* peld    = out + (size_t)KSEL * KSEL;
    float* pelp    = peld + KSEL;
    float* scalars = pelp + KSEL;

    hipFuncSetAttribute(reinterpret_cast<const void*>(&gemm256a_k),
                        hipFuncAttributeMaxDynamicSharedMemorySize, 163840);
    hipFuncSetAttribute(reinterpret_cast<const void*>(&gemm256s_k),
                        hipFuncAttributeMaxDynamicSharedMemorySize, 81920);

    compact_mask_k<<<1, 1024, 0, stream>>>((const uint8_t*)mask, (const int32_t*)mask, idx);
    gather_conv_k<<<KSEL + 1024, 256, 0, stream>>>(msp, lab, idx, W, predsB, labelsB8, wBf);
    gemm256a_k<<<2 * (KSEL / 256) * (HD / 256), 512, 163840, stream>>>(
        predsB, wBf, hPre, KSEL, HD, HD);
    ln_k<<<KSEL, 256, 0, stream>>>(hPre, hPre + (size_t)KSEL * HD, bias, gamma, beta, hB8);
    gemm256s_k<<<(KSEL / 128) * (KSEL / 128), 256, 81920, stream>>>(
        hB8, labelsB8, out, KSEL, KSEL, HD, pst);
    loss_final_k<<<KSEL / 4, 256, 0, stream>>>(pst, out, peld, pelp);
    reduce_k<<<1, 1024, 0, stream>>>(peld, pelp, scalars);
}

// Round 17
// 224.879 us; speedup vs baseline: 1.2025x; 1.2025x over previous
//
#include <hip/hip_runtime.h>
#include <cstdint>

#define NROWS 32768
#define HD    1024
#define KSEL  8192
#define LN_EPS 1e-12f
#define PD_EPS 1e-6f

typedef unsigned short u16;
typedef float  f32x4  __attribute__((ext_vector_type(4)));
typedef int    v8i    __attribute__((ext_vector_type(8)));
typedef int    v4i    __attribute__((ext_vector_type(4)));

// ---------------- fp8 e4m3 packing ----------------
__device__ inline uint32_t enc_e4m3(float f) {
    union { float f; uint32_t u; } x; x.f = f;
    uint32_t s = (x.u >> 31) << 7;
    float a = fabsf(f);
    if (a >= 448.f) return s | 0x7e;
    if (a < 0.001953125f) {
        int q = (int)(a * 512.f + 0.5f);
        return s | (uint32_t)q;
    }
    int e; float m = frexpf(a, &e);
    int E = e - 1 + 7;
    int q = (int)((m * 2.f - 1.f) * 8.f + 0.5f);
    if (q == 8) { q = 0; E += 1; }
    if (E >= 16) return s | 0x7e;
    if (E <= 0) { int qq = (int)(a * 512.f + 0.5f); return s | (uint32_t)qq; }
    return s | (uint32_t)(E << 3) | (uint32_t)q;
}

__device__ inline uint32_t pack4_f8(float a, float b, float c, float d) {
#if defined(__has_builtin) && __has_builtin(__builtin_amdgcn_cvt_pk_fp8_f32)
    int v = __builtin_amdgcn_cvt_pk_fp8_f32(a, b, 0, false);
    v = __builtin_amdgcn_cvt_pk_fp8_f32(c, d, v, true);
    return (uint32_t)v;
#else
    return enc_e4m3(a) | (enc_e4m3(b) << 8) | (enc_e4m3(c) << 16) | (enc_e4m3(d) << 24);
#endif
}

// ---------------- mask compaction (layout-robust) ----------------
__global__ void compact_mask_k(const uint8_t* mb, const int32_t* mi, int* idx) {
    __shared__ int cnt[1024];
    __shared__ int tmp[1024];
    __shared__ int mode_s;
    const int t = threadIdx.x;
    const int per = NROWS / 1024;      // 32
    const int base = t * per;
    int c0 = 0;
    for (int i = 0; i < per; ++i) c0 += (mb[base + i] != 0);
    tmp[t] = c0;
    __syncthreads();
    for (int off = 512; off > 0; off >>= 1) {
        if (t < off) tmp[t] += tmp[t + off];
        __syncthreads();
    }
    if (t == 0) mode_s = (tmp[0] == KSEL) ? 0 : 1;
    __syncthreads();
    const int mode = mode_s;
    int c = c0;
    if (mode) { c = 0; for (int i = 0; i < per; ++i) c += (mi[base + i] != 0); }
    cnt[t] = c;
    __syncthreads();
    for (int off = 1; off < 1024; off <<= 1) {
        int add = (t >= off) ? cnt[t - off] : 0;
        __syncthreads();
        cnt[t] += add;
        __syncthreads();
    }
    int pos = cnt[t] - c;
    for (int i = 0; i < per; ++i) {
        bool v = mode ? (mi[base + i] != 0) : (mb[base + i] != 0);
        if (v) idx[pos++] = base + i;
    }
}

// -- gather selected rows -> fp8(preds,labels), fused with W -> fp8 --
__global__ void gather_conv_k(const float* __restrict__ msp, const float* __restrict__ lab,
                              const int* __restrict__ idx, const float* __restrict__ W,
                              uint8_t* __restrict__ predsB8, uint8_t* __restrict__ labelsB8,
                              uint8_t* __restrict__ Wb8) {
    const int b = blockIdx.x;
    const int t = threadIdx.x;
    if (b < KSEL) {
        const int src = idx[b];
        float4 p = *(const float4*)(msp + (size_t)src * HD + t * 4);
        float4 q = *(const float4*)(lab + (size_t)src * HD + t * 4);
        *(uint32_t*)(predsB8  + (size_t)b * HD + t * 4) = pack4_f8(p.x, p.y, p.z, p.w);
        *(uint32_t*)(labelsB8 + (size_t)b * HD + t * 4) = pack4_f8(q.x, q.y, q.z, q.w);
    } else {
        const int i = ((b - KSEL) * 256 + t) * 4;   // 1024 blocks cover HD*HD
        float4 v = *(const float4*)(W + i);
        *(uint32_t*)(Wb8 + i) = pack4_f8(v.x, v.y, v.z, v.w);
    }
}

// =======================================================================
// MX-fp8 GEMM structure (r15-proven): 256x256 tile, BK=128 fp8-bytes,
// 8 waves (2x4), mfma_scale_f32_16x16x128_f8f6f4 with UNIT scales
// (e8m0 0x7F = exact 1.0 — bit-identical to plain fp8, 2x MFMA rate;
// 32B-contiguous fragments -> b128 reads, r11 swizzle geometry).
// LDS 160KB: A triple 3x32KB @0/32768/65536, B double @98304/131072.
// One counted vmcnt(4)+barrier per K-tile; stages issued after frag
// reads (deadline = tile-end vmcnt). XCD-swizzled block id.
// gemm256a_k: GEMM1 (preds@W^T), split-K x2 (two C planes), T=4.
// gemm256s_k: GEMM2 (h@labels^T) + fused softmax partials, T=8.
// =======================================================================
#define STAGE8(XPTR, ROWBASE, KT, I, LBASE) do {                                     \
    const int f_ = (I) * 512 + tid;                                                  \
    const int r_ = f_ >> 3;                                                          \
    const int sp_ = (f_ & 7) ^ (r_ & 7);                                             \
    const uint8_t* g_ = (XPTR) + (size_t)((ROWBASE) + r_) * Kd + koff + (KT) * 128 + sp_ * 16; \
    __builtin_amdgcn_global_load_lds(                                                \
        (const __attribute__((address_space(1))) void*)g_,                           \
        (__attribute__((address_space(3))) void*)(lds8 + (LBASE) + f_ * 16), 16, 0, 0);\
} while (0)

__device__ inline v8i ld_frag32(const uint8_t* p0, const uint8_t* p1) {
    v4i lo = *(const v4i*)p0;
    v4i hi = *(const v4i*)p1;
    v8i r;
    r[0] = lo[0]; r[1] = lo[1]; r[2] = lo[2]; r[3] = lo[3];
    r[4] = hi[0]; r[5] = hi[1]; r[6] = hi[2]; r[7] = hi[3];
    return r;
}

// Common prologue + K-loop (needs: bid, nwg, Kd, koff, TVAL defined).
#define FP8_GEMM_BODY(TVAL)                                                           \
    const int nx  = N >> 8;                                                           \
    int wg  = ((nwg & 7) == 0) ? ((bid & 7) * (nwg >> 3) + (bid >> 3)) : bid;         \
    const int bm = wg / nx, bn = wg % nx;                                             \
    const size_t brow = (size_t)bm << 8, bcol = (size_t)bn << 8;                      \
    const int tid = threadIdx.x;                                                      \
    const int l = tid & 63, wid = tid >> 6;                                           \
    const int wm = wid >> 2, wn = wid & 3;                                            \
    const int lr = l & 15, lq = l >> 4;                                               \
    const int sw = lr & 7;                                                            \
    f32x4 acc[8][4] = {};                                                             \
    const int arow = (wm * 128 + lr) * 128;                                           \
    const int brow2 = (wn * 64 + lr) * 128;                                           \
    const int f0 = ((lq * 2 + 0) ^ sw) * 16;                                          \
    const int f1 = ((lq * 2 + 1) ^ sw) * 16;                                          \
    _Pragma("unroll")                                                                 \
    for (int i = 0; i < 4; ++i) STAGE8(A,  brow, 0, i, 0);                            \
    _Pragma("unroll")                                                                 \
    for (int i = 0; i < 4; ++i) STAGE8(Bt, bcol, 0, i, 98304);                        \
    _Pragma("unroll")                                                                 \
    for (int i = 0; i < 4; ++i) STAGE8(A,  brow, 1, i, 32768);                        \
    asm volatile("s_waitcnt vmcnt(4)" ::: "memory");                                  \
    __builtin_amdgcn_s_barrier();                                                     \
    const int T = (TVAL);                                                             \
    int abi = 0;                                                                      \
    _Pragma("unroll 1")                                                               \
    for (int t = 0; t < T; ++t) {                                                     \
        const int aB = abi * 32768;                                                   \
        const int bB = 98304 + (t & 1) * 32768;                                       \
        const int aN = (abi >= 1 ? abi - 1 : 2) * 32768;                              \
        const int bN = 98304 + ((t + 1) & 1) * 32768;                                 \
        v8i a8[8], b8[4];                                                             \
        _Pragma("unroll")                                                             \
        for (int mi = 0; mi < 8; ++mi)                                                \
            a8[mi] = ld_frag32(lds8 + aB + arow + mi * 2048 + f0,                     \
                               lds8 + aB + arow + mi * 2048 + f1);                    \
        _Pragma("unroll")                                                             \
        for (int ni = 0; ni < 4; ++ni)                                                \
            b8[ni] = ld_frag32(lds8 + bB + brow2 + ni * 2048 + f0,                    \
                               lds8 + bB + brow2 + ni * 2048 + f1);                   \
        if (t + 1 < T) {                                                              \
            STAGE8(Bt, bcol, t + 1, 0, bN); STAGE8(Bt, bcol, t + 1, 1, bN);           \
            STAGE8(Bt, bcol, t + 1, 2, bN); STAGE8(Bt, bcol, t + 1, 3, bN);           \
        }                                                                             \
        if (t + 2 < T) {                                                              \
            STAGE8(A, brow, t + 2, 0, aN); STAGE8(A, brow, t + 2, 1, aN);             \
            STAGE8(A, brow, t + 2, 2, aN); STAGE8(A, brow, t + 2, 3, aN);             \
        }                                                                             \
        _Pragma("unroll")                                                             \
        for (int mi = 0; mi < 8; ++mi) {                                              \
            _Pragma("unroll")                                                         \
            for (int ni = 0; ni < 4; ++ni)                                            \
                acc[mi][ni] = __builtin_amdgcn_mfma_scale_f32_16x16x128_f8f6f4(       \
                    a8[mi], b8[ni], acc[mi][ni],                                      \
                    0, 0, 0, 0x7f7f7f7f, 0, 0x7f7f7f7f);                              \
        }                                                                             \
        if (t < T - 2) { asm volatile("s_waitcnt vmcnt(4)" ::: "memory"); }           \
        else           { asm volatile("s_waitcnt vmcnt(0)" ::: "memory"); }           \
        __builtin_amdgcn_s_barrier();                                                 \
        abi = (abi == 2) ? 0 : abi + 1;                                               \
    }

// ---------------- GEMM1: fp8, split-K x2, plain C-write ----------------
__global__ __launch_bounds__(512, 2)
void gemm256a_k(const uint8_t* __restrict__ A, const uint8_t* __restrict__ Bt,
                float* __restrict__ C, int M, int N, int Kd) {
    extern __shared__ u16 lds[];
    uint8_t* lds8 = (uint8_t*)lds;
    const int nwg = (M >> 8) * (N >> 8);
    int bid = blockIdx.x;
    const int half = (bid >= nwg) ? 1 : 0;
    if (half) bid -= nwg;
    const int KdH = Kd >> 1;
    const int koff = half * KdH;
    float* Cp = C + (size_t)half * ((size_t)M * N);
    FP8_GEMM_BODY(KdH >> 7);
    #pragma unroll
    for (int m = 0; m < 8; ++m) {
        const size_t rb = brow + wm * 128 + m * 16 + lq * 4;
        #pragma unroll
        for (int n = 0; n < 4; ++n) {
            const size_t cb = bcol + wn * 64 + n * 16 + lr;
            #pragma unroll
            for (int rr = 0; rr < 4; ++rr)
                Cp[(rb + rr) * (size_t)N + cb] = acc[m][n][rr];
        }
    }
}

// ------------- GEMM2: fp8 + fused softmax partials (r15 verbatim) -------
__global__ __launch_bounds__(512, 2)
void gemm256s_k(const uint8_t* __restrict__ A, const uint8_t* __restrict__ Bt,
                float* __restrict__ C, int M, int N, int Kd,
                float2* __restrict__ pst) {
    extern __shared__ u16 lds[];
    uint8_t* lds8 = (uint8_t*)lds;
    const int nwg = (M >> 8) * (N >> 8);
    int bid = blockIdx.x;
    const int koff = 0;
    FP8_GEMM_BODY(Kd >> 7);

    // epilogue: per-m stats (native __expf) interleaved with C stores.
    float2* sbuf = (float2*)lds8;              // [256][5] float2, padded
    #pragma unroll
    for (int m = 0; m < 8; ++m) {
        #pragma unroll
        for (int rr = 0; rr < 4; ++rr) {
            float v0 = acc[m][0][rr], v1 = acc[m][1][rr];
            float v2 = acc[m][2][rr], v3 = acc[m][3][rr];
            float mx = fmaxf(fmaxf(v0, v1), fmaxf(v2, v3));
            #pragma unroll
            for (int o = 1; o < 16; o <<= 1) mx = fmaxf(mx, __shfl_xor(mx, o));
            float se = __expf(v0 - mx) + __expf(v1 - mx) + __expf(v2 - mx) + __expf(v3 - mx);
            #pragma unroll
            for (int o = 1; o < 16; o <<= 1) se += __shfl_xor(se, o);
            if (lr == 0) {
                const int rl = wm * 128 + m * 16 + lq * 4 + rr;
                sbuf[rl * 5 + wn] = make_float2(mx, se);
            }
        }
        const size_t rb = brow + wm * 128 + m * 16 + lq * 4;
        #pragma unroll
        for (int n = 0; n < 4; ++n) {
            const size_t cb = bcol + wn * 64 + n * 16 + lr;
            #pragma unroll
            for (int rr = 0; rr < 4; ++rr)
                C[(rb + rr) * (size_t)N + cb] = acc[m][n][rr];
        }
    }
    asm volatile("s_waitcnt lgkmcnt(0)" ::: "memory");
    __builtin_amdgcn_s_barrier();
    if (tid < 256) {
        const float2 p0 = sbuf[tid * 5 + 0], p1 = sbuf[tid * 5 + 1];
        const float2 p2 = sbuf[tid * 5 + 2], p3 = sbuf[tid * 5 + 3];
        const float M2 = fmaxf(fmaxf(p0.x, p1.x), fmaxf(p2.x, p3.x));
        const float S2 = p0.y * __expf(p0.x - M2) + p1.y * __expf(p1.x - M2)
                       + p2.y * __expf(p2.x - M2) + p3.y * __expf(p3.x - M2);
        pst[(brow + tid) * (N >> 8) + bn] = make_float2(M2, S2);
    }
}

// ---------------- final per-row loss from partials + diagonal ----------
__global__ __launch_bounds__(256)
void loss_final_k(const float2* __restrict__ pst, const float* __restrict__ logits,
                  float* __restrict__ peld, float* __restrict__ pelp) {
    const int tid = threadIdx.x;
    const int wv = tid >> 6, half = (tid & 63) >> 5, l5 = tid & 31;
    const int row = blockIdx.x * 8 + wv * 2 + half;
    const float2 p = pst[(size_t)row * 32 + l5];
    const float d = logits[(size_t)row * (KSEL + 1)];   // diagonal
    float M = p.x;
    #pragma unroll
    for (int o = 1; o < 32; o <<= 1) M = fmaxf(M, __shfl_xor(M, o));
    float S = p.y * __expf(p.x - M);
    #pragma unroll
    for (int o = 1; o < 32; o <<= 1) S += __shfl_xor(S, o);
    if (l5 == 0) {
        const float pi = __expf(d - M) / S;
        peld[row] = 2.0f - 2.0f * pi + (float)(KSEL - 2) * PD_EPS;
        pelp[row] = M + __logf(S) - d;
    }
}

// ---------------- block reduce helpers ----------------
__device__ inline float blockSum(float v, float* red) {
    #pragma unroll
    for (int o = 32; o > 0; o >>= 1) v += __shfl_down(v, o);
    __syncthreads();
    if ((threadIdx.x & 63) == 0) red[threadIdx.x >> 6] = v;
    __syncthreads();
    return red[0] + red[1] + red[2] + red[3];
}

// ------- bias + LayerNorm (sum of 2 split-K planes) -> fp8 ----------
__global__ void ln_k(const float* __restrict__ Hp0, const float* __restrict__ Hp1,
                     const float* __restrict__ bias,
                     const float* __restrict__ gamma, const float* __restrict__ beta,
                     uint8_t* __restrict__ Hb8) {
    __shared__ float red[4];
    const int r = blockIdx.x, t = threadIdx.x;
    float4 x4 = *(const float4*)(Hp0 + (size_t)r * HD + t * 4);
    float4 y4 = *(const float4*)(Hp1 + (size_t)r * HD + t * 4);
    float4 b4 = *(const float4*)(bias + t * 4);
    float x[4] = { x4.x + y4.x + b4.x, x4.y + y4.y + b4.y,
                   x4.z + y4.z + b4.z, x4.w + y4.w + b4.w };
    float s = x[0] + x[1] + x[2] + x[3];
    float mu = blockSum(s, red) * (1.0f / HD);
    float d0 = x[0] - mu, d1 = x[1] - mu, d2 = x[2] - mu, d3 = x[3] - mu;
    float vs = d0 * d0 + d1 * d1 + d2 * d2 + d3 * d3;
    float var = blockSum(vs, red) * (1.0f / HD);
    float rs = rsqrtf(var + LN_EPS);
    float4 g4 = *(const float4*)(gamma + t * 4);
    float4 e4 = *(const float4*)(beta + t * 4);
    float y0 = d0 * rs * g4.x + e4.x;
    float y1 = d1 * rs * g4.y + e4.y;
    float y2 = d2 * rs * g4.z + e4.z;
    float y3 = d3 * rs * g4.w + e4.w;
    *(uint32_t*)(Hb8 + (size_t)r * HD + t * 4) = pack4_f8(y0, y1, y2, y3);
}

// ---------------- deterministic two-stage f64 reduction ----------------
__global__ __launch_bounds__(1024)
void reduce_k(const float* __restrict__ peld, const float* __restrict__ pelp,
              float* __restrict__ scalars) {
    __shared__ double red[4][16];
    const int t = threadIdx.x;
    double a = 0.0, b = 0.0, c = 0.0, d = 0.0;
    for (int i = t; i < KSEL; i += 1024) {
        const double pd = (double)peld[i];
        const double pp = (double)pelp[i];
        a += pd; b += pd * pd; c += pp; d += pp * pp;
    }
    #pragma unroll
    for (int o = 32; o > 0; o >>= 1) {
        a += __shfl_down(a, o); b += __shfl_down(b, o);
        c += __shfl_down(c, o); d += __shfl_down(d, o);
    }
    const int wv = t >> 6;
    if ((t & 63) == 0) { red[0][wv] = a; red[1][wv] = b; red[2][wv] = c; red[3][wv] = d; }
    __syncthreads();
    if (t == 0) {
        double s1 = 0, s2 = 0, s3 = 0, s4 = 0;
        #pragma unroll
        for (int i = 0; i < 16; ++i) { s1 += red[0][i]; s2 += red[1][i]; s3 += red[2][i]; s4 += red[3][i]; }
        const double Kd = (double)KSEL;
        const double denom = Kd + 1e-5;
        scalars[0] = (float)(s1 / denom);
        scalars[1] = (float)(s3 / denom);
        scalars[2] = (float)((s2 - s1 * s1 / Kd) / (Kd - 1.0));
        scalars[3] = (float)((s4 - s3 * s3 / Kd) / (Kd - 1.0));
    }
}

extern "C" void kernel_launch(void* const* d_in, const int* in_sizes, int n_in,
                              void* d_out, int out_size, void* d_ws, size_t ws_size,
                              hipStream_t stream) {
    const float* msp   = (const float*)d_in[0];
    const float* lab   = (const float*)d_in[1];
    const void*  mask  = d_in[2];
    const float* W     = (const float*)d_in[3];
    const float* bias  = (const float*)d_in[4];
    const float* gamma = (const float*)d_in[5];
    const float* beta  = (const float*)d_in[6];
    float* out = (float*)d_out;
    char*  ws  = (char*)d_ws;

    int*     idx      = (int*)ws;                            // 32 KB
    uint8_t* wB8      = (uint8_t*)(ws + 65536);              // 1 MB
    float2*  pst      = (float2*)(ws + 65536);               // 2 MB, reuses wB8 after GEMM1
    uint8_t* labelsB8 = (uint8_t*)(ws + (size_t)(4  << 20)); // 8 MB
    uint8_t* hB8      = (uint8_t*)(ws + (size_t)(20 << 20)); // 8 MB
    uint8_t* predsB8  = (uint8_t*)d_out;                     // 8 MB scratch (dead before GEMM2)
    float*   hPre     = out + ((size_t)8 << 20);             // 2 planes x 32 MB (dead before GEMM2)

    float* peld    = out + (size_t)KSEL * KSEL;
    float* pelp    = peld + KSEL;
    float* scalars = pelp + KSEL;

    hipFuncSetAttribute(reinterpret_cast<const void*>(&gemm256a_k),
                        hipFuncAttributeMaxDynamicSharedMemorySize, 163840);
    hipFuncSetAttribute(reinterpret_cast<const void*>(&gemm256s_k),
                        hipFuncAttributeMaxDynamicSharedMemorySize, 163840);

    compact_mask_k<<<1, 1024, 0, stream>>>((const uint8_t*)mask, (const int32_t*)mask, idx);
    gather_conv_k<<<KSEL + 1024, 256, 0, stream>>>(msp, lab, idx, W, predsB8, labelsB8, wB8);
    gemm256a_k<<<2 * (KSEL / 256) * (HD / 256), 512, 163840, stream>>>(
        predsB8, wB8, hPre, KSEL, HD, HD);
    ln_k<<<KSEL, 256, 0, stream>>>(hPre, hPre + (size_t)KSEL * HD, bias, gamma, beta, hB8);
    gemm256s_k<<<(KSEL / 256) * (KSEL / 256), 512, 163840, stream>>>(
        hB8, labelsB8, out, KSEL, KSEL, HD, pst);
    loss_final_k<<<KSEL / 8, 256, 0, stream>>>(pst, out, peld, pelp);
    reduce_k<<<1, 1024, 0, stream>>>(peld, pelp, scalars);
}

// Round 18
// 222.543 us; speedup vs baseline: 1.2151x; 1.0105x over previous
//
#include <hip/hip_runtime.h>
#include <cstdint>

#define NROWS 32768
#define HD    1024
#define KSEL  8192
#define LN_EPS 1e-12f
#define PD_EPS 1e-6f

typedef unsigned short u16;
typedef float  f32x4  __attribute__((ext_vector_type(4)));
typedef int    v8i    __attribute__((ext_vector_type(8)));
typedef int    v4i    __attribute__((ext_vector_type(4)));

__device__ inline u16 f2bf(float f) {
    union { float f; uint32_t u; } x; x.f = f;
    uint32_t r = (x.u + 0x7fffu + ((x.u >> 16) & 1u)) >> 16;
    return (u16)r;
}

__device__ inline float bf2f(uint32_t u) {
    union { uint32_t u; float f; } x; x.u = u << 16;
    return x.f;
}

// ---------------- fp8 e4m3 packing ----------------
__device__ inline uint32_t enc_e4m3(float f) {
    union { float f; uint32_t u; } x; x.f = f;
    uint32_t s = (x.u >> 31) << 7;
    float a = fabsf(f);
    if (a >= 448.f) return s | 0x7e;
    if (a < 0.001953125f) {
        int q = (int)(a * 512.f + 0.5f);
        return s | (uint32_t)q;
    }
    int e; float m = frexpf(a, &e);
    int E = e - 1 + 7;
    int q = (int)((m * 2.f - 1.f) * 8.f + 0.5f);
    if (q == 8) { q = 0; E += 1; }
    if (E >= 16) return s | 0x7e;
    if (E <= 0) { int qq = (int)(a * 512.f + 0.5f); return s | (uint32_t)qq; }
    return s | (uint32_t)(E << 3) | (uint32_t)q;
}

__device__ inline uint32_t pack4_f8(float a, float b, float c, float d) {
#if defined(__has_builtin) && __has_builtin(__builtin_amdgcn_cvt_pk_fp8_f32)
    int v = __builtin_amdgcn_cvt_pk_fp8_f32(a, b, 0, false);
    v = __builtin_amdgcn_cvt_pk_fp8_f32(c, d, v, true);
    return (uint32_t)v;
#else
    return enc_e4m3(a) | (enc_e4m3(b) << 8) | (enc_e4m3(c) << 16) | (enc_e4m3(d) << 24);
#endif
}

// ---------------- mask compaction (layout-robust) ----------------
__global__ void compact_mask_k(const uint8_t* mb, const int32_t* mi, int* idx) {
    __shared__ int cnt[1024];
    __shared__ int tmp[1024];
    __shared__ int mode_s;
    const int t = threadIdx.x;
    const int per = NROWS / 1024;      // 32
    const int base = t * per;
    int c0 = 0;
    for (int i = 0; i < per; ++i) c0 += (mb[base + i] != 0);
    tmp[t] = c0;
    __syncthreads();
    for (int off = 512; off > 0; off >>= 1) {
        if (t < off) tmp[t] += tmp[t + off];
        __syncthreads();
    }
    if (t == 0) mode_s = (tmp[0] == KSEL) ? 0 : 1;
    __syncthreads();
    const int mode = mode_s;
    int c = c0;
    if (mode) { c = 0; for (int i = 0; i < per; ++i) c += (mi[base + i] != 0); }
    cnt[t] = c;
    __syncthreads();
    for (int off = 1; off < 1024; off <<= 1) {
        int add = (t >= off) ? cnt[t - off] : 0;
        __syncthreads();
        cnt[t] += add;
        __syncthreads();
    }
    int pos = cnt[t] - c;
    for (int i = 0; i < per; ++i) {
        bool v = mode ? (mi[base + i] != 0) : (mb[base + i] != 0);
        if (v) idx[pos++] = base + i;
    }
}

// -- gather selected rows -> fp8(preds,labels), fused with W -> fp8 --
__global__ void gather_conv_k(const float* __restrict__ msp, const float* __restrict__ lab,
                              const int* __restrict__ idx, const float* __restrict__ W,
                              uint8_t* __restrict__ predsB8, uint8_t* __restrict__ labelsB8,
                              uint8_t* __restrict__ Wb8) {
    const int b = blockIdx.x;
    const int t = threadIdx.x;
    if (b < KSEL) {
        const int src = idx[b];
        float4 p = *(const float4*)(msp + (size_t)src * HD + t * 4);
        float4 q = *(const float4*)(lab + (size_t)src * HD + t * 4);
        *(uint32_t*)(predsB8  + (size_t)b * HD + t * 4) = pack4_f8(p.x, p.y, p.z, p.w);
        *(uint32_t*)(labelsB8 + (size_t)b * HD + t * 4) = pack4_f8(q.x, q.y, q.z, q.w);
    } else {
        const int i = ((b - KSEL) * 256 + t) * 4;   // 1024 blocks cover HD*HD
        float4 v = *(const float4*)(W + i);
        *(uint32_t*)(Wb8 + i) = pack4_f8(v.x, v.y, v.z, v.w);
    }
}

// =======================================================================
// MX-fp8 GEMM structure (r15-proven): 256x256 tile, BK=128 fp8-bytes,
// 8 waves (2x4), mfma_scale_f32_16x16x128_f8f6f4 with UNIT scales
// (e8m0 0x7F = exact 1.0 — bit-identical to plain fp8, 2x MFMA rate;
// 32B-contiguous fragments -> b128 reads, r11 swizzle geometry).
// LDS 160KB: A triple 3x32KB @0/32768/65536, B double @98304/131072.
// One counted vmcnt(4)+barrier per K-tile; stages issued after frag
// reads. gemm256a_k: GEMM1, split-K x2, bf16 C planes (r18: halves the
// hPre round-trip traffic; bf16 half-sum error ~0.2% << fp8's 3%).
// gemm256s_k: GEMM2 + fused softmax partials, f32 logits out.
// =======================================================================
#define STAGE8(XPTR, ROWBASE, KT, I, LBASE) do {                                     \
    const int f_ = (I) * 512 + tid;                                                  \
    const int r_ = f_ >> 3;                                                          \
    const int sp_ = (f_ & 7) ^ (r_ & 7);                                             \
    const uint8_t* g_ = (XPTR) + (size_t)((ROWBASE) + r_) * Kd + koff + (KT) * 128 + sp_ * 16; \
    __builtin_amdgcn_global_load_lds(                                                \
        (const __attribute__((address_space(1))) void*)g_,                           \
        (__attribute__((address_space(3))) void*)(lds8 + (LBASE) + f_ * 16), 16, 0, 0);\
} while (0)

__device__ inline v8i ld_frag32(const uint8_t* p0, const uint8_t* p1) {
    v4i lo = *(const v4i*)p0;
    v4i hi = *(const v4i*)p1;
    v8i r;
    r[0] = lo[0]; r[1] = lo[1]; r[2] = lo[2]; r[3] = lo[3];
    r[4] = hi[0]; r[5] = hi[1]; r[6] = hi[2]; r[7] = hi[3];
    return r;
}

// Common prologue + K-loop (needs: bid, nwg, Kd, koff, TVAL defined).
#define FP8_GEMM_BODY(TVAL)                                                           \
    const int nx  = N >> 8;                                                           \
    int wg  = ((nwg & 7) == 0) ? ((bid & 7) * (nwg >> 3) + (bid >> 3)) : bid;         \
    const int bm = wg / nx, bn = wg % nx;                                             \
    const size_t brow = (size_t)bm << 8, bcol = (size_t)bn << 8;                      \
    const int tid = threadIdx.x;                                                      \
    const int l = tid & 63, wid = tid >> 6;                                           \
    const int wm = wid >> 2, wn = wid & 3;                                            \
    const int lr = l & 15, lq = l >> 4;                                               \
    const int sw = lr & 7;                                                            \
    f32x4 acc[8][4] = {};                                                             \
    const int arow = (wm * 128 + lr) * 128;                                           \
    const int brow2 = (wn * 64 + lr) * 128;                                           \
    const int f0 = ((lq * 2 + 0) ^ sw) * 16;                                          \
    const int f1 = ((lq * 2 + 1) ^ sw) * 16;                                          \
    _Pragma("unroll")                                                                 \
    for (int i = 0; i < 4; ++i) STAGE8(A,  brow, 0, i, 0);                            \
    _Pragma("unroll")                                                                 \
    for (int i = 0; i < 4; ++i) STAGE8(Bt, bcol, 0, i, 98304);                        \
    _Pragma("unroll")                                                                 \
    for (int i = 0; i < 4; ++i) STAGE8(A,  brow, 1, i, 32768);                        \
    asm volatile("s_waitcnt vmcnt(4)" ::: "memory");                                  \
    __builtin_amdgcn_s_barrier();                                                     \
    const int T = (TVAL);                                                             \
    int abi = 0;                                                                      \
    _Pragma("unroll 1")                                                               \
    for (int t = 0; t < T; ++t) {                                                     \
        const int aB = abi * 32768;                                                   \
        const int bB = 98304 + (t & 1) * 32768;                                       \
        const int aN = (abi >= 1 ? abi - 1 : 2) * 32768;                              \
        const int bN = 98304 + ((t + 1) & 1) * 32768;                                 \
        v8i a8[8], b8[4];                                                             \
        _Pragma("unroll")                                                             \
        for (int mi = 0; mi < 8; ++mi)                                                \
            a8[mi] = ld_frag32(lds8 + aB + arow + mi * 2048 + f0,                     \
                               lds8 + aB + arow + mi * 2048 + f1);                    \
        _Pragma("unroll")                                                             \
        for (int ni = 0; ni < 4; ++ni)                                                \
            b8[ni] = ld_frag32(lds8 + bB + brow2 + ni * 2048 + f0,                    \
                               lds8 + bB + brow2 + ni * 2048 + f1);                   \
        if (t + 1 < T) {                                                              \
            STAGE8(Bt, bcol, t + 1, 0, bN); STAGE8(Bt, bcol, t + 1, 1, bN);           \
            STAGE8(Bt, bcol, t + 1, 2, bN); STAGE8(Bt, bcol, t + 1, 3, bN);           \
        }                                                                             \
        if (t + 2 < T) {                                                              \
            STAGE8(A, brow, t + 2, 0, aN); STAGE8(A, brow, t + 2, 1, aN);             \
            STAGE8(A, brow, t + 2, 2, aN); STAGE8(A, brow, t + 2, 3, aN);             \
        }                                                                             \
        _Pragma("unroll")                                                             \
        for (int mi = 0; mi < 8; ++mi) {                                              \
            _Pragma("unroll")                                                         \
            for (int ni = 0; ni < 4; ++ni)                                            \
                acc[mi][ni] = __builtin_amdgcn_mfma_scale_f32_16x16x128_f8f6f4(       \
                    a8[mi], b8[ni], acc[mi][ni],                                      \
                    0, 0, 0, 0x7f7f7f7f, 0, 0x7f7f7f7f);                              \
        }                                                                             \
        if (t < T - 2) { asm volatile("s_waitcnt vmcnt(4)" ::: "memory"); }           \
        else           { asm volatile("s_waitcnt vmcnt(0)" ::: "memory"); }           \
        __builtin_amdgcn_s_barrier();                                                 \
        abi = (abi == 2) ? 0 : abi + 1;                                               \
    }

// -------- GEMM1: fp8, split-K x2, bf16 C planes (pair-packed stores) ----
__global__ __launch_bounds__(512, 2)
void gemm256a_k(const uint8_t* __restrict__ A, const uint8_t* __restrict__ Bt,
                u16* __restrict__ C, int M, int N, int Kd) {
    extern __shared__ u16 lds[];
    uint8_t* lds8 = (uint8_t*)lds;
    const int nwg = (M >> 8) * (N >> 8);
    int bid = blockIdx.x;
    const int half = (bid >= nwg) ? 1 : 0;
    if (half) bid -= nwg;
    const int KdH = Kd >> 1;
    const int koff = half * KdH;
    u16* Cp = C + (size_t)half * ((size_t)M * N);
    FP8_GEMM_BODY(KdH >> 7);
    #pragma unroll
    for (int m = 0; m < 8; ++m) {
        const size_t rb = brow + wm * 128 + m * 16 + lq * 4;
        #pragma unroll
        for (int n = 0; n < 4; ++n) {
            const size_t cb = bcol + wn * 64 + n * 16 + lr;
            #pragma unroll
            for (int rr = 0; rr < 4; ++rr) {
                const float v = acc[m][n][rr];
                const float w = __shfl_xor(v, 1);
                if (!(lr & 1)) {
                    const uint32_t pk = (uint32_t)f2bf(v) | ((uint32_t)f2bf(w) << 16);
                    *(uint32_t*)(Cp + (rb + rr) * (size_t)N + cb) = pk;
                }
            }
        }
    }
}

// ------------- GEMM2: fp8 + fused softmax partials (r15 verbatim) -------
__global__ __launch_bounds__(512, 2)
void gemm256s_k(const uint8_t* __restrict__ A, const uint8_t* __restrict__ Bt,
                float* __restrict__ C, int M, int N, int Kd,
                float2* __restrict__ pst) {
    extern __shared__ u16 lds[];
    uint8_t* lds8 = (uint8_t*)lds;
    const int nwg = (M >> 8) * (N >> 8);
    int bid = blockIdx.x;
    const int koff = 0;
    FP8_GEMM_BODY(Kd >> 7);

    // epilogue: per-m stats (native __expf) interleaved with C stores.
    float2* sbuf = (float2*)lds8;              // [256][5] float2, padded
    #pragma unroll
    for (int m = 0; m < 8; ++m) {
        #pragma unroll
        for (int rr = 0; rr < 4; ++rr) {
            float v0 = acc[m][0][rr], v1 = acc[m][1][rr];
            float v2 = acc[m][2][rr], v3 = acc[m][3][rr];
            float mx = fmaxf(fmaxf(v0, v1), fmaxf(v2, v3));
            #pragma unroll
            for (int o = 1; o < 16; o <<= 1) mx = fmaxf(mx, __shfl_xor(mx, o));
            float se = __expf(v0 - mx) + __expf(v1 - mx) + __expf(v2 - mx) + __expf(v3 - mx);
            #pragma unroll
            for (int o = 1; o < 16; o <<= 1) se += __shfl_xor(se, o);
            if (lr == 0) {
                const int rl = wm * 128 + m * 16 + lq * 4 + rr;
                sbuf[rl * 5 + wn] = make_float2(mx, se);
            }
        }
        const size_t rb = brow + wm * 128 + m * 16 + lq * 4;
        #pragma unroll
        for (int n = 0; n < 4; ++n) {
            const size_t cb = bcol + wn * 64 + n * 16 + lr;
            #pragma unroll
            for (int rr = 0; rr < 4; ++rr)
                C[(rb + rr) * (size_t)N + cb] = acc[m][n][rr];
        }
    }
    asm volatile("s_waitcnt lgkmcnt(0)" ::: "memory");
    __builtin_amdgcn_s_barrier();
    if (tid < 256) {
        const float2 p0 = sbuf[tid * 5 + 0], p1 = sbuf[tid * 5 + 1];
        const float2 p2 = sbuf[tid * 5 + 2], p3 = sbuf[tid * 5 + 3];
        const float M2 = fmaxf(fmaxf(p0.x, p1.x), fmaxf(p2.x, p3.x));
        const float S2 = p0.y * __expf(p0.x - M2) + p1.y * __expf(p1.x - M2)
                       + p2.y * __expf(p2.x - M2) + p3.y * __expf(p3.x - M2);
        pst[(brow + tid) * (N >> 8) + bn] = make_float2(M2, S2);
    }
}

// ---------------- final per-row loss from partials + diagonal ----------
__global__ __launch_bounds__(256)
void loss_final_k(const float2* __restrict__ pst, const float* __restrict__ logits,
                  float* __restrict__ peld, float* __restrict__ pelp) {
    const int tid = threadIdx.x;
    const int wv = tid >> 6, half = (tid & 63) >> 5, l5 = tid & 31;
    const int row = blockIdx.x * 8 + wv * 2 + half;
    const float2 p = pst[(size_t)row * 32 + l5];
    const float d = logits[(size_t)row * (KSEL + 1)];   // diagonal
    float M = p.x;
    #pragma unroll
    for (int o = 1; o < 32; o <<= 1) M = fmaxf(M, __shfl_xor(M, o));
    float S = p.y * __expf(p.x - M);
    #pragma unroll
    for (int o = 1; o < 32; o <<= 1) S += __shfl_xor(S, o);
    if (l5 == 0) {
        const float pi = __expf(d - M) / S;
        peld[row] = 2.0f - 2.0f * pi + (float)(KSEL - 2) * PD_EPS;
        pelp[row] = M + __logf(S) - d;
    }
}

// ---------------- block reduce helpers ----------------
__device__ inline float blockSum(float v, float* red) {
    #pragma unroll
    for (int o = 32; o > 0; o >>= 1) v += __shfl_down(v, o);
    __syncthreads();
    if ((threadIdx.x & 63) == 0) red[threadIdx.x >> 6] = v;
    __syncthreads();
    return red[0] + red[1] + red[2] + red[3];
}

// --- bias + LayerNorm (sum of 2 bf16 split-K planes) -> fp8 ----------
__global__ void ln_k(const u16* __restrict__ Hp0, const u16* __restrict__ Hp1,
                     const float* __restrict__ bias,
                     const float* __restrict__ gamma, const float* __restrict__ beta,
                     uint8_t* __restrict__ Hb8) {
    __shared__ float red[4];
    const int r = blockIdx.x, t = threadIdx.x;
    uint2 ua = *(const uint2*)(Hp0 + (size_t)r * HD + t * 4);
    uint2 ub = *(const uint2*)(Hp1 + (size_t)r * HD + t * 4);
    float4 b4 = *(const float4*)(bias + t * 4);
    float x[4] = {
        bf2f(ua.x & 0xffff) + bf2f(ub.x & 0xffff) + b4.x,
        bf2f(ua.x >> 16)    + bf2f(ub.x >> 16)    + b4.y,
        bf2f(ua.y & 0xffff) + bf2f(ub.y & 0xffff) + b4.z,
        bf2f(ua.y >> 16)    + bf2f(ub.y >> 16)    + b4.w
    };
    float s = x[0] + x[1] + x[2] + x[3];
    float mu = blockSum(s, red) * (1.0f / HD);
    float d0 = x[0] - mu, d1 = x[1] - mu, d2 = x[2] - mu, d3 = x[3] - mu;
    float vs = d0 * d0 + d1 * d1 + d2 * d2 + d3 * d3;
    float var = blockSum(vs, red) * (1.0f / HD);
    float rs = rsqrtf(var + LN_EPS);
    float4 g4 = *(const float4*)(gamma + t * 4);
    float4 e4 = *(const float4*)(beta + t * 4);
    float y0 = d0 * rs * g4.x + e4.x;
    float y1 = d1 * rs * g4.y + e4.y;
    float y2 = d2 * rs * g4.z + e4.z;
    float y3 = d3 * rs * g4.w + e4.w;
    *(uint32_t*)(Hb8 + (size_t)r * HD + t * 4) = pack4_f8(y0, y1, y2, y3);
}

// ---------------- deterministic two-stage f64 reduction ----------------
__global__ __launch_bounds__(1024)
void reduce_k(const float* __restrict__ peld, const float* __restrict__ pelp,
              float* __restrict__ scalars) {
    __shared__ double red[4][16];
    const int t = threadIdx.x;
    double a = 0.0, b = 0.0, c = 0.0, d = 0.0;
    for (int i = t; i < KSEL; i += 1024) {
        const double pd = (double)peld[i];
        const double pp = (double)pelp[i];
        a += pd; b += pd * pd; c += pp; d += pp * pp;
    }
    #pragma unroll
    for (int o = 32; o > 0; o >>= 1) {
        a += __shfl_down(a, o); b += __shfl_down(b, o);
        c += __shfl_down(c, o); d += __shfl_down(d, o);
    }
    const int wv = t >> 6;
    if ((t & 63) == 0) { red[0][wv] = a; red[1][wv] = b; red[2][wv] = c; red[3][wv] = d; }
    __syncthreads();
    if (t == 0) {
        double s1 = 0, s2 = 0, s3 = 0, s4 = 0;
        #pragma unroll
        for (int i = 0; i < 16; ++i) { s1 += red[0][i]; s2 += red[1][i]; s3 += red[2][i]; s4 += red[3][i]; }
        const double Kd = (double)KSEL;
        const double denom = Kd + 1e-5;
        scalars[0] = (float)(s1 / denom);
        scalars[1] = (float)(s3 / denom);
        scalars[2] = (float)((s2 - s1 * s1 / Kd) / (Kd - 1.0));
        scalars[3] = (float)((s4 - s3 * s3 / Kd) / (Kd - 1.0));
    }
}

extern "C" void kernel_launch(void* const* d_in, const int* in_sizes, int n_in,
                              void* d_out, int out_size, void* d_ws, size_t ws_size,
                              hipStream_t stream) {
    const float* msp   = (const float*)d_in[0];
    const float* lab   = (const float*)d_in[1];
    const void*  mask  = d_in[2];
    const float* W     = (const float*)d_in[3];
    const float* bias  = (const float*)d_in[4];
    const float* gamma = (const float*)d_in[5];
    const float* beta  = (const float*)d_in[6];
    float* out = (float*)d_out;
    char*  ws  = (char*)d_ws;

    int*     idx      = (int*)ws;                            // 32 KB
    uint8_t* wB8      = (uint8_t*)(ws + 65536);              // 1 MB
    float2*  pst      = (float2*)(ws + 65536);               // 2 MB, reuses wB8 after GEMM1
    uint8_t* labelsB8 = (uint8_t*)(ws + (size_t)(4  << 20)); // 8 MB
    uint8_t* hB8      = (uint8_t*)(ws + (size_t)(20 << 20)); // 8 MB
    uint8_t* predsB8  = (uint8_t*)d_out;                     // 8 MB scratch (dead before GEMM2)
    u16*     hPre     = (u16*)(out + ((size_t)8 << 20));     // 2 bf16 planes x 16 MB

    float* peld    = out + (size_t)KSEL * KSEL;
    float* pelp    = peld + KSEL;
    float* scalars = pelp + KSEL;

    hipFuncSetAttribute(reinterpret_cast<const void*>(&gemm256a_k),
                        hipFuncAttributeMaxDynamicSharedMemorySize, 163840);
    hipFuncSetAttribute(reinterpret_cast<const void*>(&gemm256s_k),
                        hipFuncAttributeMaxDynamicSharedMemorySize, 163840);

    compact_mask_k<<<1, 1024, 0, stream>>>((const uint8_t*)mask, (const int32_t*)mask, idx);
    gather_conv_k<<<KSEL + 1024, 256, 0, stream>>>(msp, lab, idx, W, predsB8, labelsB8, wB8);
    gemm256a_k<<<2 * (KSEL / 256) * (HD / 256), 512, 163840, stream>>>(
        predsB8, wB8, hPre, KSEL, HD, HD);
    ln_k<<<KSEL, 256, 0, stream>>>(hPre, hPre + (size_t)KSEL * HD, bias, gamma, beta, hB8);
    gemm256s_k<<<(KSEL / 256) * (KSEL / 256), 512, 163840, stream>>>(
        hB8, labelsB8, out, KSEL, KSEL, HD, pst);
    loss_final_k<<<KSEL / 8, 256, 0, stream>>>(pst, out, peld, pelp);
    reduce_k<<<1, 1024, 0, stream>>>(peld, pelp, scalars);
}